// Round 3
// baseline (965.436 us; speedup 1.0000x reference)
//
#include <hip/hip_runtime.h>
#include <hip/hip_bf16.h>
#include <stdint.h>

#define N_TOK 8192
#define DIN   1024
#define DHID  4096
#define DOUT  1024
#define NE    8

typedef __attribute__((ext_vector_type(8))) __bf16 bf16x8;
typedef __attribute__((ext_vector_type(4))) float  f32x4;
typedef __attribute__((ext_vector_type(8))) unsigned short u16x8;

// RNE float->bf16 (finite inputs)
__device__ __forceinline__ unsigned short f2bfu(float f) {
    union { float f; unsigned u; } a; a.f = f;
    unsigned r = a.u + 0x7FFF + ((a.u >> 16) & 1);
    return (unsigned short)(r >> 16);
}

__device__ __forceinline__ void gload_lds16(const void* g, void* l) {
    __builtin_amdgcn_global_load_lds(
        (__attribute__((address_space(1))) void*)(void*)g,
        (__attribute__((address_space(3))) void*)l,
        16, 0, 0);
}

// ---- 64x64 cast+transpose tile as a device function (256-thread blocks) ----
// in [R][C] f32 (expert bz) -> out [C][R] bf16. t = 64x65 f32 LDS staging.
__device__ __forceinline__ void transpose_tile(const float* __restrict__ in,
                                               unsigned short* __restrict__ out,
                                               int R, int C, int bx, int by, int bz,
                                               float (*t)[65]) {
    const size_t RC = (size_t)R * C;
    const float* ine = in + (size_t)bz * RC;
    unsigned short* oute = out + (size_t)bz * RC;
    int c0 = bx * 64, r0 = by * 64;
    int tid = threadIdx.x;
    __syncthreads();   // LDS region free (prev tile's reads / prev phase done)
    #pragma unroll
    for (int it = 0; it < 4; it++) {
        int idx = it * 256 + tid;
        int r = idx >> 4, cq = (idx & 15) * 4;
        float4 v = *(const float4*)(ine + (size_t)(r0 + r) * C + c0 + cq);
        t[r][cq] = v.x; t[r][cq + 1] = v.y; t[r][cq + 2] = v.z; t[r][cq + 3] = v.w;
    }
    __syncthreads();
    #pragma unroll
    for (int it = 0; it < 2; it++) {
        int u = it * 256 + tid;
        int c = u >> 3, g = (u & 7) * 8;
        u16x8 o;
        #pragma unroll
        for (int v = 0; v < 8; v++) o[v] = f2bfu(t[g + v][c]);
        *(u16x8*)(oute + (size_t)(c0 + c) * R + r0 + g) = o;
    }
}

// ---------------- gating + fused W1 transpose + out-zeroing ----------------
__global__ void gate_kernel(const float* __restrict__ x, const float* __restrict__ Wg,
                            const float* __restrict__ bg, int* __restrict__ counts,
                            int* __restrict__ tok_list, int* __restrict__ slot_list,
                            float* __restrict__ wslot, unsigned short* __restrict__ xb,
                            const float* __restrict__ W1, unsigned short* __restrict__ w1t,
                            float* __restrict__ out_zero) {
    __shared__ float tg[64][65];
    int wv = threadIdx.x >> 6, lane = threadIdx.x & 63;
    int n = blockIdx.x * 4 + wv;
    float acc[NE];
    #pragma unroll
    for (int e = 0; e < NE; e++) acc[e] = 0.f;
    const float* xr = x + (size_t)n * DIN;
    unsigned short* xbr = xb + (size_t)n * DIN;
    #pragma unroll
    for (int i = 0; i < DIN / 256; i++) {
        int d = i * 256 + lane * 4;
        float4 xv = *(const float4*)(xr + d);
        ushort4 o;
        o.x = f2bfu(xv.x); o.y = f2bfu(xv.y); o.z = f2bfu(xv.z); o.w = f2bfu(xv.w);
        *(ushort4*)(xbr + d) = o;
        const float* w = Wg + (size_t)d * NE;
        #pragma unroll
        for (int u = 0; u < 4; u++) {
            float xs = (&xv.x)[u];
            float4 w0 = *(const float4*)(w + u * NE);
            float4 w1 = *(const float4*)(w + u * NE + 4);
            acc[0] += xs * w0.x; acc[1] += xs * w0.y; acc[2] += xs * w0.z; acc[3] += xs * w0.w;
            acc[4] += xs * w1.x; acc[5] += xs * w1.y; acc[6] += xs * w1.z; acc[7] += xs * w1.w;
        }
    }
    #pragma unroll
    for (int off = 32; off; off >>= 1)
        #pragma unroll
        for (int e = 0; e < NE; e++) acc[e] += __shfl_down(acc[e], off);
    if (lane == 0) {
        float s[NE], p[NE];
        float mx = -1e30f;
        #pragma unroll
        for (int e = 0; e < NE; e++) { s[e] = acc[e] + bg[e]; mx = fmaxf(mx, s[e]); }
        float sum = 0.f;
        #pragma unroll
        for (int e = 0; e < NE; e++) { p[e] = expf(s[e] - mx); sum += p[e]; }
        float inv = 1.f / sum;
        int e0 = 0;
        #pragma unroll
        for (int e = 1; e < NE; e++) if (s[e] > s[e0]) e0 = e;
        int e1 = (e0 == 0) ? 1 : 0;
        #pragma unroll
        for (int e = 0; e < NE; e++) if (e != e0 && s[e] > s[e1]) e1 = e;
        float p0 = p[e0] * inv, p1 = p[e1] * inv;
        float rn = 1.f / (p0 + p1 + 1e-8f);
        int pos0 = atomicAdd(&counts[e0], 1);
        tok_list[e0 * N_TOK + pos0] = n; slot_list[e0 * N_TOK + pos0] = 2 * n;     wslot[e0 * N_TOK + pos0] = p0 * rn;
        int pos1 = atomicAdd(&counts[e1], 1);
        tok_list[e1 * N_TOK + pos1] = n; slot_list[e1 * N_TOK + pos1] = 2 * n + 1; wslot[e1 * N_TOK + pos1] = p1 * rn;
    }
    // zero the output accumulator (replaces the 33MB hipMemsetAsync node); out
    // is consumed by GEMM2 which launches after GEMM1 -> ordering satisfied.
    {
        float4 z = {0.f, 0.f, 0.f, 0.f};
        float* ob = out_zero + ((size_t)blockIdx.x * 256 + threadIdx.x) * 16;
        #pragma unroll
        for (int j = 0; j < 4; j++) *(float4*)(ob + j * 4) = z;
    }
    // fused W1 transpose: tiles laid out as grid (DHID/64=64, DIN/64=16, NE)
    #pragma unroll 1
    for (int j = 0; j < 4; j++) {
        int id = blockIdx.x * 4 + j;
        int bx = id & 63, by = (id >> 6) & 15, bz = id >> 10;
        transpose_tile(W1, w1t, DIN, DHID, bx, by, bz, tg);
    }
}

// ---------------- persistent grouped gather-GEMM, BMx128 tile, BK=64, bf16 MFMA ----------------
// Proven R0 sync structure (stage -> sync -> 2x[ds_read frags + MFMA] -> sync), generalized to
// BM rows. GEMM1 uses BM=256 (per wave: 64 MFMA vs 24 ds_read per K-step -> matrix pipe outweighs
// LDS pipe; was 32:16 at BM=128) with 96 blocks/expert (grid 768, 3 blocks/CU at 51KB LDS).
// GEMM2 stays the proven BM=128 / SPLITK=2 / grid 1024 config. Expert e = blockIdx&7 == XCD id
// (grid % 8 == 0) so each expert's B panel stays on one XCD's L2. XOR-swizzled staging (k8^ric),
// 0 bank conflicts (verified R0/R2). GEMM1 epilogue: wave-private LDS repack (144B-padded rows,
// <=2-way write conflict, conflict-free b128 readback) -> coalesced 128B u16x8 row segments
// instead of 128 scattered 2B stores/thread.
template <int BM, int KDIM, int NDIM, bool IS_GEMM1, int SPLITK, int NBLK>
__global__ __launch_bounds__(256, (BM == 256) ? 3 : 4)
void moe_gemm(const unsigned short* __restrict__ Asrc, const unsigned short* __restrict__ Bt,
              const float* __restrict__ bias, unsigned short* __restrict__ Hdst,
              float* __restrict__ Odst, const int* __restrict__ counts,
              const int* __restrict__ tok_list, const int* __restrict__ slot_list,
              const float* __restrict__ wslot,
              const float* __restrict__ W2src, unsigned short* __restrict__ w2t_dst) {
    constexpr int NT_N = NDIM / 128;
    constexpr int NT_M = N_TOK / BM;
    constexpr int KLEN = KDIM / SPLITK;
    constexpr int MFR  = BM / 32;          // m-frags per wave (wave tile = (BM/2) x 64)
    constexpr int NA   = BM / 32;          // A gload_lds per lane per K-step

    int e = blockIdx.x & 7;
    int local = blockIdx.x >> 3;           // 0..NBLK-1
    int count = counts[e];

    __shared__ __align__(16) unsigned short pool[(BM + 128) * 64];  // As | Bs
    unsigned short* As = pool;
    unsigned short* Bs = pool + BM * 64;
    __shared__ int rowid_s[BM];
    __shared__ int outid_s[BM];
    __shared__ float w_s[BM];

    int tid = threadIdx.x;
    int lane = tid & 63;
    int wv = tid >> 6;
    int ric = lane >> 3;
    int k8  = (lane & 7) ^ ric;
    int wm = (wv >> 1) * (BM / 2), wn = (wv & 1) * 64;
    int r16 = lane & 15, quad = lane >> 4;

    bool tdone = !IS_GEMM1;

    for (int w = local; ; w += NBLK) {
        int tile_n = w % NT_N;
        int r = w / NT_N;
        int kh = r % SPLITK;
        int tile_m = r / SPLITK;
        if (tile_m >= NT_M) break;
        if (tile_m * BM >= count) break;    // tile_m monotone => nothing left

        __syncthreads();   // prior item's epilogue reads of outid_s/w_s must finish
        for (int t0 = tid; t0 < BM; t0 += 256) {
            int rr = tile_m * BM + t0;
            if (rr >= count) rr = tile_m * BM;
            int base = e * N_TOK + rr;
            if (IS_GEMM1) { rowid_s[t0] = tok_list[base]; outid_s[t0] = slot_list[base]; }
            else          { rowid_s[t0] = slot_list[base]; outid_s[t0] = tok_list[base]; w_s[t0] = wslot[base]; }
        }
        __syncthreads();

        const int k0 = kh * KLEN;
        const unsigned short* aptr[NA];
        const unsigned short* bptr[4];
        #pragma unroll
        for (int i = 0; i < NA; i++) {
            int c = wv * NA + i;
            aptr[i] = Asrc + (size_t)rowid_s[c * 8 + ric] * KDIM + k0 + k8 * 8;
        }
        #pragma unroll
        for (int i = 0; i < 4; i++) {
            int c = wv * 4 + i;
            bptr[i] = Bt + ((size_t)e * NDIM + tile_n * 128 + c * 8 + ric) * KDIM + k0 + k8 * 8;
        }

        f32x4 acc[MFR][4];
        #pragma unroll
        for (int i = 0; i < MFR; i++)
            #pragma unroll
            for (int j = 0; j < 4; j++) acc[i][j] = (f32x4){0.f, 0.f, 0.f, 0.f};

        for (int kk = 0; kk < KLEN / 64; kk++) {
            #pragma unroll
            for (int i = 0; i < NA; i++)
                gload_lds16(aptr[i] + kk * 64, (void*)(As + (wv * NA + i) * 512));
            #pragma unroll
            for (int i = 0; i < 4; i++)
                gload_lds16(bptr[i] + kk * 64, (void*)(Bs + (wv * 4 + i) * 512));
            __syncthreads();
            #pragma unroll
            for (int kh2 = 0; kh2 < 2; kh2++) {
                int swk = ((kh2 * 4 + quad) ^ (r16 & 7)) * 8;   // un-swizzle at read time
                bf16x8 av[MFR], bv[4];
                #pragma unroll
                for (int i = 0; i < MFR; i++)
                    av[i] = *(const bf16x8*)(As + (wm + i * 16 + r16) * 64 + swk);
                #pragma unroll
                for (int j = 0; j < 4; j++)
                    bv[j] = *(const bf16x8*)(Bs + (wn + j * 16 + r16) * 64 + swk);
                #pragma unroll
                for (int i = 0; i < MFR; i++)
                    #pragma unroll
                    for (int j = 0; j < 4; j++)
                        acc[i][j] = __builtin_amdgcn_mfma_f32_16x16x32_bf16(av[i], bv[j], acc[i][j], 0, 0, 0);
            }
            __syncthreads();
        }

        // bias per wave-column
        float bias_r[4];
        #pragma unroll
        for (int j = 0; j < 4; j++)
            bias_r[j] = bias[(size_t)e * NDIM + tile_n * 128 + wn + j * 16 + r16];

        if constexpr (IS_GEMM1) {
            // wave-private LDS repack: 64x64 bf16 chunks at 144B row stride -> coalesced stores.
            // Slices live in the (dead until next loop-top sync) staging pool: 4 x 12KB.
            char* sl = (char*)pool + wv * 12288;
            #pragma unroll
            for (int ch = 0; ch < MFR / 4; ch++) {
                #pragma unroll
                for (int fi = 0; fi < 4; fi++) {
                    int f = ch * 4 + fi;
                    #pragma unroll
                    for (int reg = 0; reg < 4; reg++) {
                        int rl = fi * 16 + quad * 4 + reg;          // 0..63 local row
                        #pragma unroll
                        for (int j = 0; j < 4; j++) {
                            int col = j * 16 + r16;                 // 0..63 local col
                            float v = fmaxf(acc[f][j][reg] + bias_r[j], 0.f);
                            *(unsigned short*)(sl + rl * 144 + col * 2) = f2bfu(v);
                        }
                    }
                }
                asm volatile("s_waitcnt lgkmcnt(0)" ::: "memory");  // wave-local publish
                int rgrp = lane >> 3, s8 = lane & 7;
                #pragma unroll
                for (int it = 0; it < 8; it++) {
                    int rl = it * 8 + rgrp;
                    int rr = wm + ch * 64 + rl;
                    u16x8 vv = *(const u16x8*)(sl + rl * 144 + s8 * 16);
                    if (tile_m * BM + rr < count)
                        *(u16x8*)(Hdst + (size_t)outid_s[rr] * NDIM + tile_n * 128 + wn + s8 * 8) = vv;
                }
                asm volatile("s_waitcnt lgkmcnt(0)" ::: "memory");  // reads done before next chunk
            }
        } else {
            #pragma unroll
            for (int i = 0; i < MFR; i++) {
                #pragma unroll
                for (int reg = 0; reg < 4; reg++) {
                    int rr = wm + i * 16 + quad * 4 + reg;
                    if (tile_m * BM + rr >= count) continue;
                    #pragma unroll
                    for (int j = 0; j < 4; j++) {
                        int col = tile_n * 128 + wn + j * 16 + r16;
                        float v = acc[i][j][reg];
                        if (kh == 0) v += bias_r[j];
                        atomicAdd(&Odst[(size_t)outid_s[rr] * NDIM + col], w_s[rr] * v);
                    }
                }
            }
        }

        // fused W2 transpose after the first item (overlaps other blocks' compute)
        if constexpr (IS_GEMM1) {
            if (!tdone) {
                tdone = true;
                float (*t)[65] = (float(*)[65])pool;   // 16.7KB <= pool, As/Bs dead here
                #pragma unroll 1
                for (int j = 0; j < 11; j++) {
                    int id = blockIdx.x * 11 + j;      // tiles: grid (DOUT/64=16, DHID/64=64, NE)
                    if (id >= 8192) break;
                    int bx = id & 15, by = (id >> 4) & 63, bz = id >> 10;
                    transpose_tile(W2src, w2t_dst, DHID, DOUT, bx, by, bz, t);
                }
            }
        }
    }

    // blocks that ran out of items early still owe their transpose chunk
    if constexpr (IS_GEMM1) {
        if (!tdone) {
            float (*t)[65] = (float(*)[65])pool;
            #pragma unroll 1
            for (int j = 0; j < 11; j++) {
                int id = blockIdx.x * 11 + j;
                if (id >= 8192) break;
                int bx = id & 15, by = (id >> 4) & 63, bz = id >> 10;
                transpose_tile(W2src, w2t_dst, DHID, DOUT, bx, by, bz, t);
            }
        }
    }
}

extern "C" void kernel_launch(void* const* d_in, const int* in_sizes, int n_in,
                              void* d_out, int out_size, void* d_ws, size_t ws_size,
                              hipStream_t stream) {
    const float* x  = (const float*)d_in[0];
    const float* W1 = (const float*)d_in[1];
    const float* b1 = (const float*)d_in[2];
    const float* W2 = (const float*)d_in[3];
    const float* b2 = (const float*)d_in[4];
    const float* Wg = (const float*)d_in[5];
    const float* bg = (const float*)d_in[6];
    float* out = (float*)d_out;

    char* ws = (char*)d_ws;
    unsigned short* xb  = (unsigned short*)(ws + 0);            // 16 MB
    unsigned short* w1t = (unsigned short*)(ws + 16777216);     // 64 MB  [E][DHID][DIN]
    unsigned short* w2t = (unsigned short*)(ws + 83886080);     // 64 MB  [E][DOUT][DHID]
    unsigned short* h   = (unsigned short*)(ws + 150994944);    // 128 MB [2N][DHID]
    int*   counts    = (int*)(ws + 285212672);
    int*   tok_list  = (int*)(ws + 285212928);
    int*   slot_list = (int*)(ws + 285475072);
    float* wslot     = (float*)(ws + 285737216);

    hipMemsetAsync(counts, 0, 256, stream);

    gate_kernel<<<N_TOK / 4, 256, 0, stream>>>(x, Wg, bg, counts, tok_list, slot_list, wslot, xb,
                                               W1, w1t, out);

    moe_gemm<256, DIN, DHID, true, 1, 96><<<768, 256, 0, stream>>>(
        xb, w1t, b1, h, nullptr, counts, tok_list, slot_list, wslot, W2, w2t);
    moe_gemm<128, DHID, DOUT, false, 2, 128><<<1024, 256, 0, stream>>>(
        h, w2t, b2, nullptr, out, counts, tok_list, slot_list, wslot, nullptr, nullptr);
}